// Round 6
// baseline (49.608 us; speedup 1.0000x reference)
//
#include <hip/hip_runtime.h>

#define IN_H 200
#define IN_W 200
#define NCH  256
#define NROI 512
#define OUT_HW 49
#define PLANE (IN_H * IN_W)

// ---------------- kernel 1: NCHW f32 -> NHWC bf16 ----------------
__global__ __launch_bounds__(256) void transpose_bf16_kernel(
    const float* __restrict__ in, ushort* __restrict__ nhwc) {
  __shared__ ushort t[64][260];
  const int blk = blockIdx.x;
  const int hwt = blk % 625;
  const int b   = blk / 625;
  const int w = threadIdx.x >> 6, l = threadIdx.x & 63;
  const int hw0 = hwt * 64;

  const float* src = in + (size_t)b * NCH * PLANE + hw0;
#pragma unroll 4
  for (int i = 0; i < 64; ++i) {
    const int c = w * 64 + i;
    const float v = src[(size_t)c * PLANE + l];
    const unsigned u = __float_as_uint(v);
    const unsigned r = (u + 0x7fffu + ((u >> 16) & 1u)) >> 16;  // RN-even
    t[l][c] = (ushort)r;
  }
  __syncthreads();

  ushort* dst = nhwc + ((size_t)b * PLANE + hw0) * NCH;
#pragma unroll
  for (int m = threadIdx.x; m < 64 * 64; m += 256) {
    const int h = m >> 6;
    const int q = m & 63;
    *(ushort4*)(dst + (size_t)h * NCH + q * 4) = *(const ushort4*)&t[h][q * 4];
  }
}

// ---------------- kernel 1b: spatial sort of roi indices ----------------
// key = (batch, cy-bucket, cx-bucket); deterministic stable rank.
__global__ __launch_bounds__(512) void roi_sort_kernel(
    const float* __restrict__ rois, int* __restrict__ perm) {
  __shared__ int keys[NROI];
  __shared__ int offs[128];
  __shared__ int hist[128];
  const int t = threadIdx.x;
  {
    const float* r = rois + t * 5;
    const int b = (int)r[0];
    const float cx = (r[1] + r[3]) * 0.125f;   // feature-space center
    const float cy = (r[2] + r[4]) * 0.125f;
    int xb = (int)(cx * 0.04f);                // 25-px buckets
    int yb = (int)(cy * 0.04f);
    xb = min(max(xb, 0), 7);
    yb = min(max(yb, 0), 7);
    keys[t] = (b << 6) | (yb << 3) | xb;
  }
  if (t < 128) hist[t] = 0;
  __syncthreads();
  atomicAdd(&hist[keys[t]], 1);
  __syncthreads();
  if (t == 0) {
    int s = 0;
    for (int i = 0; i < 128; ++i) { offs[i] = s; s += hist[i]; }
  }
  __syncthreads();
  const int myk = keys[t];
  int rank = 0;
  for (int j = 0; j < t; ++j) rank += (keys[j] == myk) ? 1 : 0;  // stable
  perm[offs[myk] + rank] = t;
}

// ---------------- kernel 2: ROIAlign from bf16 NHWC (perm-indirected) ----------------
__global__ __launch_bounds__(512) void roi_nhwc_bf16_kernel(
    const ushort* __restrict__ nhwc,
    const float* __restrict__ rois,
    const int* __restrict__ perm,
    float* __restrict__ out) {
  __shared__ float sout[NCH * OUT_HW];  // 50176 B

  // chunk swizzle: XCD (bid%8) gets contiguous sorted chunk of 64 rois
  const int k  = perm[(blockIdx.x & 7) * 64 + (blockIdx.x >> 3)];
  const int t  = threadIdx.x;
  const int pg = t >> 6;          // 0..7 (wave-uniform)
  const int c0 = (t & 63) * 4;

  const float* r = rois + k * 5;
  const int   b   = (int)r[0];
  const float x1s = r[1] * 0.25f;
  const float y1s = r[2] * 0.25f;
  const float x2s = r[3] * 0.25f;
  const float y2s = r[4] * 0.25f;
  const float roi_w = fmaxf(x2s - x1s, 1.0f);
  const float roi_h = fmaxf(y2s - y1s, 1.0f);
  const float bw = roi_w / 7.0f;
  const float bh = roi_h / 7.0f;

  const bool valid = (y1s + 0.25f * bh >= -1.0f) && (y1s + 6.75f * bh <= (float)IN_H) &&
                     (x1s + 0.25f * bw >= -1.0f) && (x1s + 6.75f * bw <= (float)IN_W);
  const float scale = valid ? 0.25f : 0.0f;

  const ushort* base = nhwc + (size_t)b * PLANE * NCH;

  for (int p = pg; p < OUT_HW; p += 8) {
    const int ph = p / 7;
    const int pw = p - ph * 7;
    const float ybase = y1s + bh * (float)ph;
    const float xbase = x1s + bw * (float)pw;

    float acc0 = 0.0f, acc1 = 0.0f, acc2 = 0.0f, acc3 = 0.0f;
#pragma unroll
    for (int iy = 0; iy < 2; ++iy) {
      const float y  = ybase + (bh * 0.5f) * ((float)iy + 0.5f);
      const float yc = fminf(fmaxf(y, 0.0f), (float)(IN_H - 1));
      const float ylf = floorf(yc);
      const int   yl  = (int)ylf;
      const int   yh  = min(yl + 1, IN_H - 1);
      const float ly  = yc - ylf;
      const float hy  = 1.0f - ly;
      const ushort* rowl = base + (size_t)yl * IN_W * NCH + c0;
      const ushort* rowh = base + (size_t)yh * IN_W * NCH + c0;
#pragma unroll
      for (int ix = 0; ix < 2; ++ix) {
        const float x  = xbase + (bw * 0.5f) * ((float)ix + 0.5f);
        const float xc = fminf(fmaxf(x, 0.0f), (float)(IN_W - 1));
        const float xlf = floorf(xc);
        const int   xl  = (int)xlf;
        const int   xh  = min(xl + 1, IN_W - 1);
        const float lx  = xc - xlf;
        const float hx  = 1.0f - lx;

        const ushort4 u1 = *(const ushort4*)(rowl + (size_t)xl * NCH);
        const ushort4 u2 = *(const ushort4*)(rowl + (size_t)xh * NCH);
        const ushort4 u3 = *(const ushort4*)(rowh + (size_t)xl * NCH);
        const ushort4 u4 = *(const ushort4*)(rowh + (size_t)xh * NCH);

        const float w1 = hy * hx, w2 = hy * lx, w3 = ly * hx, w4 = ly * lx;
#define BF(us) __uint_as_float(((unsigned)(us)) << 16)
        acc0 += w1 * BF(u1.x) + w2 * BF(u2.x) + w3 * BF(u3.x) + w4 * BF(u4.x);
        acc1 += w1 * BF(u1.y) + w2 * BF(u2.y) + w3 * BF(u3.y) + w4 * BF(u4.y);
        acc2 += w1 * BF(u1.z) + w2 * BF(u2.z) + w3 * BF(u3.z) + w4 * BF(u4.z);
        acc3 += w1 * BF(u1.w) + w2 * BF(u2.w) + w3 * BF(u3.w) + w4 * BF(u4.w);
#undef BF
      }
    }
    sout[(c0 + 0) * OUT_HW + p] = acc0 * scale;
    sout[(c0 + 1) * OUT_HW + p] = acc1 * scale;
    sout[(c0 + 2) * OUT_HW + p] = acc2 * scale;
    sout[(c0 + 3) * OUT_HW + p] = acc3 * scale;
  }
  __syncthreads();

  float4* o4 = (float4*)(out + (size_t)k * NCH * OUT_HW);
  const float4* s4 = (const float4*)sout;
  for (int m = t; m < (NCH * OUT_HW) / 4; m += 512) o4[m] = s4[m];
}

// ---------------- fallback (ws too small): direct gather, f32 NCHW ----------------
__global__ __launch_bounds__(256) void roi_align_fallback(
    const float* __restrict__ input,
    const float* __restrict__ rois,
    float* __restrict__ out) {
  const int blk  = blockIdx.x;
  const int k    = blk >> 6;
  const int cg   = blk & 63;
  const int wave = threadIdx.x >> 6;
  const int lane = threadIdx.x & 63;
  const int c    = (cg << 2) + wave;

  const float* r = rois + k * 5;
  const int   b   = (int)r[0];
  const float x1s = r[1] * 0.25f;
  const float y1s = r[2] * 0.25f;
  const float roi_w = fmaxf(r[3] * 0.25f - x1s, 1.0f);
  const float roi_h = fmaxf(r[4] * 0.25f - y1s, 1.0f);
  const float bw = roi_w / 7.0f;
  const float bh = roi_h / 7.0f;
  const bool valid = (y1s + 0.25f * bh >= -1.0f) && (y1s + 6.75f * bh <= (float)IN_H) &&
                     (x1s + 0.25f * bw >= -1.0f) && (x1s + 6.75f * bw <= (float)IN_W);
  if (lane >= OUT_HW) return;
  const int ph = lane / 7;
  const int pw = lane - ph * 7;
  const float* plane = input + ((size_t)(b * NCH + c)) * PLANE;
  const float ybase = y1s + bh * (float)ph;
  const float xbase = x1s + bw * (float)pw;
  float acc = 0.0f;
#pragma unroll
  for (int iy = 0; iy < 2; ++iy) {
    const float y  = ybase + (bh * 0.5f) * ((float)iy + 0.5f);
    const float yc = fminf(fmaxf(y, 0.0f), (float)(IN_H - 1));
    const float ylf = floorf(yc);
    const int yl = (int)ylf;
    const int yh = min(yl + 1, IN_H - 1);
    const float ly = yc - ylf, hy = 1.0f - ly;
#pragma unroll
    for (int ix = 0; ix < 2; ++ix) {
      const float x  = xbase + (bw * 0.5f) * ((float)ix + 0.5f);
      const float xc = fminf(fmaxf(x, 0.0f), (float)(IN_W - 1));
      const float xlf = floorf(xc);
      const int xl = (int)xlf;
      const int xh = min(xl + 1, IN_W - 1);
      const float lx = xc - xlf, hx = 1.0f - lx;
      const float* row_l = plane + yl * IN_W;
      const float* row_h = plane + yh * IN_W;
      acc += hy * hx * row_l[xl] + hy * lx * row_l[xh] +
             ly * hx * row_h[xl] + ly * lx * row_h[xh];
    }
  }
  out[((size_t)k * NCH + c) * OUT_HW + lane] = valid ? acc * 0.25f : 0.0f;
}

extern "C" void kernel_launch(void* const* d_in, const int* in_sizes, int n_in,
                              void* d_out, int out_size, void* d_ws, size_t ws_size,
                              hipStream_t stream) {
  const float* input = (const float*)d_in[0];
  const float* rois  = (const float*)d_in[1];
  float* out = (float*)d_out;

  const size_t nhwc_bytes = (size_t)2 * PLANE * NCH * sizeof(ushort);  // 40.96 MB
  const size_t need = nhwc_bytes + NROI * sizeof(int);
  if (ws_size >= need) {
    ushort* nhwc = (ushort*)d_ws;
    int* perm = (int*)((char*)d_ws + nhwc_bytes);
    transpose_bf16_kernel<<<2 * 625, 256, 0, stream>>>(input, nhwc);
    roi_sort_kernel<<<1, 512, 0, stream>>>(rois, perm);
    roi_nhwc_bf16_kernel<<<NROI, 512, 0, stream>>>(nhwc, rois, perm, out);
  } else {
    roi_align_fallback<<<NROI * (NCH / 4), 256, 0, stream>>>(input, rois, out);
  }
}

// Round 7
// 44.724 us; speedup vs baseline: 1.1092x; 1.1092x over previous
//
#include <hip/hip_runtime.h>

#define IN_H 200
#define IN_W 200
#define NCH  256
#define NROI 512
#define OUT_HW 49
#define PLANE (IN_H * IN_W)

// ---------------- kernel 1: NCHW f32 -> NHWC bf16 ----------------
__global__ __launch_bounds__(256) void transpose_bf16_kernel(
    const float* __restrict__ in, ushort* __restrict__ nhwc) {
  __shared__ ushort t[64][260];
  const int blk = blockIdx.x;
  const int hwt = blk % 625;
  const int b   = blk / 625;
  const int w = threadIdx.x >> 6, l = threadIdx.x & 63;
  const int hw0 = hwt * 64;

  const float* src = in + (size_t)b * NCH * PLANE + hw0;
#pragma unroll 4
  for (int i = 0; i < 64; ++i) {
    const int c = w * 64 + i;
    const float v = src[(size_t)c * PLANE + l];
    const unsigned u = __float_as_uint(v);
    const unsigned r = (u + 0x7fffu + ((u >> 16) & 1u)) >> 16;  // RN-even
    t[l][c] = (ushort)r;
  }
  __syncthreads();

  ushort* dst = nhwc + ((size_t)b * PLANE + hw0) * NCH;
#pragma unroll
  for (int m = threadIdx.x; m < 64 * 64; m += 256) {
    const int h = m >> 6;
    const int q = m & 63;
    *(ushort4*)(dst + (size_t)h * NCH + q * 4) = *(const ushort4*)&t[h][q * 4];
  }
}

__device__ inline void acc8(float* acc, uint4 q, float w) {
  acc[0] += w * __uint_as_float(q.x << 16);
  acc[1] += w * __uint_as_float(q.x & 0xffff0000u);
  acc[2] += w * __uint_as_float(q.y << 16);
  acc[3] += w * __uint_as_float(q.y & 0xffff0000u);
  acc[4] += w * __uint_as_float(q.z << 16);
  acc[5] += w * __uint_as_float(q.z & 0xffff0000u);
  acc[6] += w * __uint_as_float(q.w << 16);
  acc[7] += w * __uint_as_float(q.w & 0xffff0000u);
}

// ---------------- kernel 2: ROIAlign from bf16 NHWC ----------------
// block = half a roi (128 ch); 256 thr; thread: 8 ch (uint4 loads), 16 px-groups
__global__ __launch_bounds__(256) void roi_nhwc_bf16_kernel(
    const ushort* __restrict__ nhwc,
    const float* __restrict__ rois,
    float* __restrict__ out) {
  __shared__ float sout[128 * OUT_HW];  // 25088 B

  const int blk  = blockIdx.x;
  const int k    = blk >> 1;
  const int half = blk & 1;
  const int t    = threadIdx.x;
  const int pg   = t >> 4;             // 0..15
  const int cl   = (t & 15) * 8;       // local channel 0..120
  const int c0   = half * 128 + cl;

  const float* r = rois + k * 5;
  const int   b   = (int)r[0];
  const float x1s = r[1] * 0.25f;
  const float y1s = r[2] * 0.25f;
  const float x2s = r[3] * 0.25f;
  const float y2s = r[4] * 0.25f;
  const float roi_w = fmaxf(x2s - x1s, 1.0f);
  const float roi_h = fmaxf(y2s - y1s, 1.0f);
  const float bw = roi_w / 7.0f;
  const float bh = roi_h / 7.0f;

  // whole-roi validity (coords monotone: min at p=0,i=0; max at p=6,i=1)
  const bool valid = (y1s + 0.25f * bh >= -1.0f) && (y1s + 6.75f * bh <= (float)IN_H) &&
                     (x1s + 0.25f * bw >= -1.0f) && (x1s + 6.75f * bw <= (float)IN_W);
  const float scale = valid ? 0.25f : 0.0f;

  const ushort* base = nhwc + (size_t)b * PLANE * NCH + c0;

  for (int p = pg; p < OUT_HW; p += 16) {
    const int ph = p / 7;
    const int pw = p - ph * 7;
    const float ybase = y1s + bh * (float)ph;
    const float xbase = x1s + bw * (float)pw;

    float acc[8] = {0.f, 0.f, 0.f, 0.f, 0.f, 0.f, 0.f, 0.f};
#pragma unroll
    for (int iy = 0; iy < 2; ++iy) {
      const float y  = ybase + (bh * 0.5f) * ((float)iy + 0.5f);
      const float yc = fminf(fmaxf(y, 0.0f), (float)(IN_H - 1));
      const float ylf = floorf(yc);
      const int   yl  = (int)ylf;
      const int   yh  = min(yl + 1, IN_H - 1);
      const float ly  = yc - ylf;
      const float hy  = 1.0f - ly;
      const ushort* rowl = base + (size_t)yl * IN_W * NCH;
      const ushort* rowh = base + (size_t)yh * IN_W * NCH;
#pragma unroll
      for (int ix = 0; ix < 2; ++ix) {
        const float x  = xbase + (bw * 0.5f) * ((float)ix + 0.5f);
        const float xc = fminf(fmaxf(x, 0.0f), (float)(IN_W - 1));
        const float xlf = floorf(xc);
        const int   xl  = (int)xlf;
        const int   xh  = min(xl + 1, IN_W - 1);
        const float lx  = xc - xlf;
        const float hx  = 1.0f - lx;

        const uint4 q1 = *(const uint4*)(rowl + (size_t)xl * NCH);
        const uint4 q2 = *(const uint4*)(rowl + (size_t)xh * NCH);
        const uint4 q3 = *(const uint4*)(rowh + (size_t)xl * NCH);
        const uint4 q4 = *(const uint4*)(rowh + (size_t)xh * NCH);

        acc8(acc, q1, hy * hx);
        acc8(acc, q2, hy * lx);
        acc8(acc, q3, ly * hx);
        acc8(acc, q4, ly * lx);
      }
    }
#pragma unroll
    for (int j = 0; j < 8; ++j) sout[(cl + j) * OUT_HW + p] = acc[j] * scale;
  }
  __syncthreads();

  // contiguous coalesced write of this half-roi's (128,7,7) tile
  float4* o4 = (float4*)(out + ((size_t)k * NCH + half * 128) * OUT_HW);
  const float4* s4 = (const float4*)sout;
  for (int m = t; m < (128 * OUT_HW) / 4; m += 256) o4[m] = s4[m];
}

// ---------------- fallback (ws too small): direct gather, f32 NCHW ----------------
__global__ __launch_bounds__(256) void roi_align_fallback(
    const float* __restrict__ input,
    const float* __restrict__ rois,
    float* __restrict__ out) {
  const int blk  = blockIdx.x;
  const int k    = blk >> 6;
  const int cg   = blk & 63;
  const int wave = threadIdx.x >> 6;
  const int lane = threadIdx.x & 63;
  const int c    = (cg << 2) + wave;

  const float* r = rois + k * 5;
  const int   b   = (int)r[0];
  const float x1s = r[1] * 0.25f;
  const float y1s = r[2] * 0.25f;
  const float roi_w = fmaxf(r[3] * 0.25f - x1s, 1.0f);
  const float roi_h = fmaxf(r[4] * 0.25f - y1s, 1.0f);
  const float bw = roi_w / 7.0f;
  const float bh = roi_h / 7.0f;
  const bool valid = (y1s + 0.25f * bh >= -1.0f) && (y1s + 6.75f * bh <= (float)IN_H) &&
                     (x1s + 0.25f * bw >= -1.0f) && (x1s + 6.75f * bw <= (float)IN_W);
  if (lane >= OUT_HW) return;
  const int ph = lane / 7;
  const int pw = lane - ph * 7;
  const float* plane = input + ((size_t)(b * NCH + c)) * PLANE;
  const float ybase = y1s + bh * (float)ph;
  const float xbase = x1s + bw * (float)pw;
  float acc = 0.0f;
#pragma unroll
  for (int iy = 0; iy < 2; ++iy) {
    const float y  = ybase + (bh * 0.5f) * ((float)iy + 0.5f);
    const float yc = fminf(fmaxf(y, 0.0f), (float)(IN_H - 1));
    const float ylf = floorf(yc);
    const int yl = (int)ylf;
    const int yh = min(yl + 1, IN_H - 1);
    const float ly = yc - ylf, hy = 1.0f - ly;
#pragma unroll
    for (int ix = 0; ix < 2; ++ix) {
      const float x  = xbase + (bw * 0.5f) * ((float)ix + 0.5f);
      const float xc = fminf(fmaxf(x, 0.0f), (float)(IN_W - 1));
      const float xlf = floorf(xc);
      const int xl = (int)xlf;
      const int xh = min(xl + 1, IN_W - 1);
      const float lx = xc - xlf, hx = 1.0f - lx;
      const float* row_l = plane + yl * IN_W;
      const float* row_h = plane + yh * IN_W;
      acc += hy * hx * row_l[xl] + hy * lx * row_l[xh] +
             ly * hx * row_h[xl] + ly * lx * row_h[xh];
    }
  }
  out[((size_t)k * NCH + c) * OUT_HW + lane] = valid ? acc * 0.25f : 0.0f;
}

extern "C" void kernel_launch(void* const* d_in, const int* in_sizes, int n_in,
                              void* d_out, int out_size, void* d_ws, size_t ws_size,
                              hipStream_t stream) {
  const float* input = (const float*)d_in[0];
  const float* rois  = (const float*)d_in[1];
  float* out = (float*)d_out;

  const size_t need = (size_t)2 * PLANE * NCH * sizeof(ushort);  // 40.96 MB
  if (ws_size >= need) {
    ushort* nhwc = (ushort*)d_ws;
    transpose_bf16_kernel<<<2 * 625, 256, 0, stream>>>(input, nhwc);
    roi_nhwc_bf16_kernel<<<NROI * 2, 256, 0, stream>>>(nhwc, rois, out);
  } else {
    roi_align_fallback<<<NROI * (NCH / 4), 256, 0, stream>>>(input, rois, out);
  }
}